// Round 5
// baseline (170.641 us; speedup 1.0000x reference)
//
#include <hip/hip_runtime.h>

#define Hd 512
#define N2d 16
#define Rd 32
#define Ld 4096
#define NCHUNK 128
#define CLEN (Ld / NCHUNK)   // 32
#define NCH (Hd * N2d)       // 8192 chains

// ---------------------------------------------------------------------------
// Kernel 0a: transpose dt_w[H][R] -> dt_wT[R][H].
// ---------------------------------------------------------------------------
__global__ __launch_bounds__(256) void k_tw(const float* __restrict__ dt_w,
                                            float* __restrict__ dt_wT) {
    int idx = blockIdx.x * 256 + threadIdx.x;
    int r = idx >> 9;
    int h = idx & 511;
    dt_wT[idx] = dt_w[h * Rd + r];
}

// ---------------------------------------------------------------------------
// Kernel 0b: per-h A-structure info: (Are0, Aim0, dA, fast_flag).
// fast when Are uniform and Aim arithmetic across all 16 n (S4D init).
// ---------------------------------------------------------------------------
__global__ __launch_bounds__(256) void k_hinfo(const float* __restrict__ A_log,
                                               const float* __restrict__ A_im,
                                               float4* __restrict__ hinfo) {
    int h = blockIdx.x * 256 + threadIdx.x;
    if (h >= Hd) return;
    float Are0 = -__expf(A_log[h * N2d]);
    float Aim0 = A_im[h * N2d];
    float dA = A_im[h * N2d + 1] - Aim0;
    bool ok = true;
    for (int j = 1; j < N2d; ++j) {
        float a = -__expf(A_log[h * N2d + j]);
        ok = ok && (a == Are0) && (A_im[h * N2d + j] == Aim0 + j * dA);
    }
    hinfo[h] = make_float4(Are0, Aim0, dA, ok ? 1.f : 0.f);
}

// ---------------------------------------------------------------------------
// Kernel 1: dt = softplus(u@xprojT@dtwT + b); writes du[l][h] = (dt, u/dt).
// ---------------------------------------------------------------------------
__global__ __launch_bounds__(256) void k_dt(const float* __restrict__ u,
                                            const float* __restrict__ xproj_w,
                                            const float* __restrict__ dt_wT,
                                            const float* __restrict__ dt_b,
                                            float2* __restrict__ du_out) {
    __shared__ float u_s[8][Hd];
    __shared__ float dtu_s[8][Rd];
    const int t = threadIdx.x;
    const int l0 = blockIdx.x * 8;

    #pragma unroll
    for (int i = 0; i < 16; ++i) {
        int idx = t + i * 256;
        ((float*)u_s)[idx] = u[l0 * Hd + idx];
    }
    __syncthreads();

    const int r = t >> 3;
    const int j = t & 7;
    float part[8];
    #pragma unroll
    for (int l = 0; l < 8; ++l) part[l] = 0.f;
    for (int k = 0; k < 64; ++k) {
        float w = xproj_w[r * Hd + k * 8 + j];
        #pragma unroll
        for (int l = 0; l < 8; ++l) part[l] = fmaf(u_s[l][k * 8 + j], w, part[l]);
    }
    #pragma unroll
    for (int off = 1; off < 8; off <<= 1) {
        #pragma unroll
        for (int l = 0; l < 8; ++l) part[l] += __shfl_xor(part[l], off);
    }
    if (j == 0) {
        #pragma unroll
        for (int l = 0; l < 8; ++l) dtu_s[l][r] = part[l];
    }
    __syncthreads();

    #pragma unroll
    for (int hb = 0; hb < 2; ++hb) {
        int h = hb * 256 + t;
        float bias = dt_b[h];
        float acc[8];
        #pragma unroll
        for (int l = 0; l < 8; ++l) acc[l] = bias;
        for (int rr = 0; rr < Rd; ++rr) {
            float w = dt_wT[rr * Hd + h];
            #pragma unroll
            for (int l = 0; l < 8; ++l) acc[l] = fmaf(dtu_s[l][rr], w, acc[l]);
        }
        #pragma unroll
        for (int l = 0; l < 8; ++l) {
            float x = acc[l];
            float sp = fmaxf(x, 0.f) + log1pf(__expf(-fabsf(x)));  // softplus
            float uv = u_s[l][h];
            float us = uv * __builtin_amdgcn_rcpf(fmaxf(sp, 1e-30f));
            du_out[(l0 + l) * Hd + h] = make_float2(sp, us);
        }
    }
}

// ---------------------------------------------------------------------------
// Per-thread consts: 4 consecutive n of one h. fast when Are uniform and Aim
// arithmetic within the thread's 4 n.
// ---------------------------------------------------------------------------
__device__ __forceinline__ bool load_consts4(const float* A_log, const float* A_im,
        const float* B_param, int hnb,
        float* Are, float* Aim, float* BAr, float* BAi) {
    #pragma unroll
    for (int j = 0; j < 4; ++j) {
        int hn = hnb + j;
        Are[j] = -__expf(A_log[hn]);
        Aim[j] = A_im[hn];
        float Bre = B_param[2 * hn];
        float Bim = B_param[2 * hn + 1];
        float inv = __builtin_amdgcn_rcpf(Are[j] * Are[j] + Aim[j] * Aim[j]);
        BAr[j] = (Bre * Are[j] + Bim * Aim[j]) * inv;   // Bc*conj(A)/|A|^2
        BAi[j] = (Bim * Are[j] - Bre * Aim[j]) * inv;
    }
    float d1 = Aim[1] - Aim[0], d2 = Aim[2] - Aim[1], d3 = Aim[3] - Aim[2];
    return (Are[1] == Are[0]) && (Are[2] == Are[0]) && (Are[3] == Are[0]) &&
           (d1 == d2) && (d2 == d3);
}

// ---------------------------------------------------------------------------
// Kernel 2 (phase 1): chunk-local scan (h0=0). Emits per-step partial output
// y4[l][h][q] = sum over own 4 n of Re(C*h_local) (+ u*D on q==0), in-chunk
// cumulative dt T[l][h] (q==0), and chunk summaries P = exp(A*sum_dt), S.
// 4 n per thread; block 256 = 64 h x 4 q; grid (NCHUNK, H/64).
// ---------------------------------------------------------------------------
__global__ __launch_bounds__(256) void k_chunk(const float2* __restrict__ du,
        const float* __restrict__ A_log, const float* __restrict__ A_im,
        const float* __restrict__ B_param, const float* __restrict__ C_param,
        const float* __restrict__ Dp,
        float2* __restrict__ Pbuf, float2* __restrict__ Sbuf,
        float* __restrict__ y4, float* __restrict__ T) {
    const int t = threadIdx.x;
    const int q = t & 3;
    const int h = blockIdx.y * 64 + (t >> 2);
    const int c = blockIdx.x;
    const int hnb = h * N2d + q * 4;
    float Are[4], Aim[4], BAr[4], BAi[4], Cre[4], Cim[4];
    const bool fast = load_consts4(A_log, A_im, B_param, hnb, Are, Aim, BAr, BAi);
    #pragma unroll
    for (int j = 0; j < 4; ++j) {
        Cre[j] = C_param[2 * (hnb + j)];
        Cim[j] = C_param[2 * (hnb + j) + 1];
    }
    const float Dv = Dp[h];
    float sr[4] = {0.f, 0.f, 0.f, 0.f}, si[4] = {0.f, 0.f, 0.f, 0.f};
    float sdt = 0.f;
    const int lbase = c * CLEN;
    if (fast) {
        const float Are0 = Are[0], Aim0 = Aim[0], dA = Aim[1] - Aim[0];
        #pragma unroll 4
        for (int k = 0; k < CLEN; ++k) {
            int l = lbase + k;
            float2 d = du[l * Hd + h];
            float dtv = d.x, us = d.y;
            sdt += dtv;
            float er = __expf(dtv * Are0);
            float s0, c0, sd, cd;
            __sincosf(dtv * Aim0, &s0, &c0);
            __sincosf(dtv * dA, &sd, &cd);
            float ar = er * c0, ai = er * s0;
            float yq = 0.f;
            #pragma unroll
            for (int j = 0; j < 4; ++j) {
                float gr = fmaf(ar, us, -us);
                float gi = ai * us;
                float nr = fmaf(ar, sr[j], fmaf(-ai, si[j], fmaf(gr, BAr[j], -gi * BAi[j])));
                float ni = fmaf(ar, si[j], fmaf( ai, sr[j], fmaf(gr, BAi[j],  gi * BAr[j])));
                sr[j] = nr; si[j] = ni;
                yq = fmaf(nr, Cre[j], fmaf(-ni, Cim[j], yq));
                if (j < 3) {
                    float tr = fmaf(ar, cd, -ai * sd);
                    ai = fmaf(ai, cd, ar * sd);
                    ar = tr;
                }
            }
            if (q == 0) {
                yq = fmaf(dtv * us, Dv, yq);   // + u*D
                T[l * Hd + h] = sdt;
            }
            y4[((l * Hd + h) << 2) | q] = yq;
        }
    } else {
        #pragma unroll 4
        for (int k = 0; k < CLEN; ++k) {
            int l = lbase + k;
            float2 d = du[l * Hd + h];
            float dtv = d.x, us = d.y;
            sdt += dtv;
            float yq = 0.f;
            #pragma unroll
            for (int j = 0; j < 4; ++j) {
                float er = __expf(dtv * Are[j]);
                float s, cc;
                __sincosf(dtv * Aim[j], &s, &cc);
                float ar = er * cc, ai = er * s;
                float gr = fmaf(ar, us, -us);
                float gi = ai * us;
                float nr = fmaf(ar, sr[j], fmaf(-ai, si[j], fmaf(gr, BAr[j], -gi * BAi[j])));
                float ni = fmaf(ar, si[j], fmaf( ai, sr[j], fmaf(gr, BAi[j],  gi * BAr[j])));
                sr[j] = nr; si[j] = ni;
                yq = fmaf(nr, Cre[j], fmaf(-ni, Cim[j], yq));
            }
            if (q == 0) {
                yq = fmaf(dtv * us, Dv, yq);
                T[l * Hd + h] = sdt;
            }
            y4[((l * Hd + h) << 2) | q] = yq;
        }
    }
    int base = c * NCH + hnb;
    #pragma unroll
    for (int j = 0; j < 4; ++j) {
        float er = __expf(sdt * Are[j]);
        float s, cc;
        __sincosf(sdt * Aim[j], &s, &cc);
        Pbuf[base + j] = make_float2(er * cc, er * s);
        Sbuf[base + j] = make_float2(sr[j], si[j]);
    }
}

// ---------------------------------------------------------------------------
// Kernel 3 (phase 2): sequential combine over chunks; emits G[c][hn] = C*h0_c.
// ---------------------------------------------------------------------------
__global__ __launch_bounds__(256) void k_prefix(const float2* __restrict__ Pbuf,
        const float2* __restrict__ Sbuf, const float* __restrict__ C_param,
        float2* __restrict__ Gbuf) {
    int idx = blockIdx.x * 256 + threadIdx.x;  // 0..8191 = h*16+n
    float Cre = C_param[2 * idx];
    float Cim = C_param[2 * idx + 1];
    float hr = 0.f, hi = 0.f;
    for (int b = 0; b < NCHUNK / 8; ++b) {
        float2 tp[8], ts[8];
        #pragma unroll
        for (int i = 0; i < 8; ++i) {
            tp[i] = Pbuf[(b * 8 + i) * NCH + idx];
            ts[i] = Sbuf[(b * 8 + i) * NCH + idx];
        }
        #pragma unroll
        for (int i = 0; i < 8; ++i) {
            Gbuf[(b * 8 + i) * NCH + idx] =
                make_float2(fmaf(Cre, hr, -Cim * hi), fmaf(Cre, hi, Cim * hr));
            float nr = fmaf(tp[i].x, hr, fmaf(-tp[i].y, hi, ts[i].x));
            float ni = fmaf(tp[i].x, hi, fmaf( tp[i].y, hr, ts[i].y));
            hr = nr; hi = ni;
        }
    }
}

// ---------------------------------------------------------------------------
// Kernel 4 (phase 3): correction — no recurrence, no shuffles.
// y[l,h] = sum_q y4[l,h,q] + Re( e^{Are*T} * sum_n G_n * cis(Aim_n*T) ).
// One thread per (l,h); 8192 blocks.
// ---------------------------------------------------------------------------
__global__ __launch_bounds__(256) void k_corr(const float* __restrict__ y4,
        const float* __restrict__ T, const float2* __restrict__ Gbuf,
        const float4* __restrict__ hinfo, const float* __restrict__ A_log,
        const float* __restrict__ A_im, float* __restrict__ out) {
    int gid = blockIdx.x * 256 + threadIdx.x;   // 0..L*H-1
    int l = gid >> 9;
    int h = gid & 511;
    int c = l / CLEN;
    float4 yv = ((const float4*)y4)[gid];
    float ysum = (yv.x + yv.y) + (yv.z + yv.w);
    float Tv = T[gid];
    float4 hi4 = hinfo[h];
    const float4* G4 = (const float4*)(Gbuf + (size_t)c * NCH + h * N2d); // 8 float4
    float acc = 0.f;
    if (hi4.w != 0.f) {
        float er = __expf(Tv * hi4.x);
        float s0, c0, sd, cd;
        __sincosf(Tv * hi4.y, &s0, &c0);
        __sincosf(Tv * hi4.z, &sd, &cd);
        float rr = c0, ri = s0;
        #pragma unroll
        for (int j = 0; j < 8; ++j) {
            float4 g = G4[j];
            acc = fmaf(g.x, rr, fmaf(-g.y, ri, acc));
            float tr = fmaf(rr, cd, -ri * sd);
            ri = fmaf(ri, cd, rr * sd);
            rr = tr;
            acc = fmaf(g.z, rr, fmaf(-g.w, ri, acc));
            tr = fmaf(rr, cd, -ri * sd);
            ri = fmaf(ri, cd, rr * sd);
            rr = tr;
        }
        acc *= er;
    } else {
        const float2* G2 = (const float2*)G4;
        #pragma unroll 4
        for (int j = 0; j < N2d; ++j) {
            int hn = h * N2d + j;
            float Are = -__expf(A_log[hn]);
            float er = __expf(Tv * Are);
            float s, cc;
            __sincosf(Tv * A_im[hn], &s, &cc);
            float2 g = G2[j];
            acc = fmaf(g.x * er, cc, fmaf(-g.y * er, s, acc));
        }
    }
    out[gid] = ysum + acc;
}

extern "C" void kernel_launch(void* const* d_in, const int* in_sizes, int n_in,
                              void* d_out, int out_size, void* d_ws, size_t ws_size,
                              hipStream_t stream) {
    const float* u        = (const float*)d_in[0];
    const float* A_log    = (const float*)d_in[1];
    const float* A_im     = (const float*)d_in[2];
    const float* B_param  = (const float*)d_in[3];
    const float* C_param  = (const float*)d_in[4];
    const float* Dp       = (const float*)d_in[5];
    const float* dt_w     = (const float*)d_in[6];
    const float* dt_b     = (const float*)d_in[7];
    const float* xproj_w  = (const float*)d_in[8];

    // ws: du[L*H f2] | P[NCHUNK*NCH f2] | S[..] | G[..] | y4[L*H*4 f] |
    //     T[L*H f] | dt_wT[R*H f] | hinfo[H f4]
    float2* du   = (float2*)d_ws;
    float2* Pbuf = du + (size_t)Ld * Hd;
    float2* Sbuf = Pbuf + (size_t)NCHUNK * NCH;
    float2* Gbuf = Sbuf + (size_t)NCHUNK * NCH;
    float*  y4   = (float*)(Gbuf + (size_t)NCHUNK * NCH);
    float*  T    = y4 + (size_t)Ld * Hd * 4;
    float*  dt_wT = T + (size_t)Ld * Hd;
    float4* hinfo = (float4*)(dt_wT + Rd * Hd);
    float*  out  = (float*)d_out;

    k_tw<<<(Rd * Hd) / 256, 256, 0, stream>>>(dt_w, dt_wT);
    k_hinfo<<<2, 256, 0, stream>>>(A_log, A_im, hinfo);
    k_dt<<<Ld / 8, 256, 0, stream>>>(u, xproj_w, dt_wT, dt_b, du);
    dim3 g2(NCHUNK, Hd / 64);
    k_chunk<<<g2, 256, 0, stream>>>(du, A_log, A_im, B_param, C_param, Dp,
                                    Pbuf, Sbuf, y4, T);
    k_prefix<<<NCH / 256, 256, 0, stream>>>(Pbuf, Sbuf, C_param, Gbuf);
    k_corr<<<(Ld * Hd) / 256, 256, 0, stream>>>(y4, T, Gbuf, hinfo,
                                                A_log, A_im, out);
}

// Round 6
// 167.777 us; speedup vs baseline: 1.0171x; 1.0171x over previous
//
#include <hip/hip_runtime.h>

#define Hd 512
#define N2d 16
#define Rd 32
#define Ld 4096
#define NCHUNK 256
#define CLEN (Ld / NCHUNK)   // 16
#define NCH (Hd * N2d)       // 8192 chains

// ---------------------------------------------------------------------------
// Kernel 0: transpose dt_w[H][R] -> dt_wT[R][H].
// ---------------------------------------------------------------------------
__global__ __launch_bounds__(256) void k_tw(const float* __restrict__ dt_w,
                                            float* __restrict__ dt_wT) {
    int idx = blockIdx.x * 256 + threadIdx.x;
    int r = idx >> 9;
    int h = idx & 511;
    dt_wT[idx] = dt_w[h * Rd + r];
}

// ---------------------------------------------------------------------------
// Kernel 1: dt = softplus(u@xprojT@dtwT + b); writes du[l][h] = (dt, u/dt).
// ---------------------------------------------------------------------------
__global__ __launch_bounds__(256) void k_dt(const float* __restrict__ u,
                                            const float* __restrict__ xproj_w,
                                            const float* __restrict__ dt_wT,
                                            const float* __restrict__ dt_b,
                                            float2* __restrict__ du_out) {
    __shared__ float u_s[8][Hd];
    __shared__ float dtu_s[8][Rd];
    const int t = threadIdx.x;
    const int l0 = blockIdx.x * 8;

    #pragma unroll
    for (int i = 0; i < 16; ++i) {
        int idx = t + i * 256;
        ((float*)u_s)[idx] = u[l0 * Hd + idx];
    }
    __syncthreads();

    const int r = t >> 3;
    const int j = t & 7;
    float part[8];
    #pragma unroll
    for (int l = 0; l < 8; ++l) part[l] = 0.f;
    for (int k = 0; k < 64; ++k) {
        float w = xproj_w[r * Hd + k * 8 + j];
        #pragma unroll
        for (int l = 0; l < 8; ++l) part[l] = fmaf(u_s[l][k * 8 + j], w, part[l]);
    }
    #pragma unroll
    for (int off = 1; off < 8; off <<= 1) {
        #pragma unroll
        for (int l = 0; l < 8; ++l) part[l] += __shfl_xor(part[l], off);
    }
    if (j == 0) {
        #pragma unroll
        for (int l = 0; l < 8; ++l) dtu_s[l][r] = part[l];
    }
    __syncthreads();

    #pragma unroll
    for (int hb = 0; hb < 2; ++hb) {
        int h = hb * 256 + t;
        float bias = dt_b[h];
        float acc[8];
        #pragma unroll
        for (int l = 0; l < 8; ++l) acc[l] = bias;
        for (int rr = 0; rr < Rd; ++rr) {
            float w = dt_wT[rr * Hd + h];
            #pragma unroll
            for (int l = 0; l < 8; ++l) acc[l] = fmaf(dtu_s[l][rr], w, acc[l]);
        }
        #pragma unroll
        for (int l = 0; l < 8; ++l) {
            float x = acc[l];
            float sp = fmaxf(x, 0.f) + log1pf(__expf(-fabsf(x)));  // softplus
            float uv = u_s[l][h];
            float us = uv * __builtin_amdgcn_rcpf(fmaxf(sp, 1e-30f));
            du_out[(l0 + l) * Hd + h] = make_float2(sp, us);
        }
    }
}

// ---------------------------------------------------------------------------
// Per-thread setup for one h, all 16 n.
// fast: Are uniform and Aim arithmetic across n (true for S4D init A=-1+i n).
// BA[j] = Bc_j / A_j (folds the ZOH division into a constant).
// ---------------------------------------------------------------------------
__device__ __forceinline__ bool setup_h(const float* __restrict__ A_log,
        const float* __restrict__ A_im, const float* __restrict__ B_param,
        int h, float& Are0, float& Aim0, float& dA,
        float* __restrict__ BAr, float* __restrict__ BAi) {
    const int hb = h * N2d;
    Are0 = -__expf(A_log[hb]);
    Aim0 = A_im[hb];
    dA = A_im[hb + 1] - Aim0;
    bool ok = true;
    #pragma unroll
    for (int j = 0; j < N2d; ++j) {
        int hn = hb + j;
        float Ar = -__expf(A_log[hn]);
        float Ai = A_im[hn];
        ok = ok && (Ar == Are0) && (Ai == fmaf((float)j, dA, Aim0));
        float Br = B_param[2 * hn];
        float Bi = B_param[2 * hn + 1];
        float inv = __builtin_amdgcn_rcpf(Ar * Ar + Ai * Ai);
        BAr[j] = (Br * Ar + Bi * Ai) * inv;
        BAi[j] = (Bi * Ar - Br * Ai) * inv;
    }
    return ok;
}

// ---------------------------------------------------------------------------
// Kernel 2 (phase 1): chunk-local scan (h0=0), all 16 n per thread.
// Emits PS[c][n][h] = (P_re, P_im, S_re, S_im), P = exp(A*sum_dt) exactly.
// Grid (NCHUNK, 2), block 256; thread -> (chunk c, hidden h).
// ---------------------------------------------------------------------------
__global__ __launch_bounds__(256) void k_chunk(const float2* __restrict__ du,
        const float* __restrict__ A_log, const float* __restrict__ A_im,
        const float* __restrict__ B_param, float4* __restrict__ PS) {
    const int h = blockIdx.y * 256 + threadIdx.x;
    const int c = blockIdx.x;
    float Are0, Aim0, dA, BAr[N2d], BAi[N2d];
    const bool fast = setup_h(A_log, A_im, B_param, h, Are0, Aim0, dA, BAr, BAi);
    float sr[N2d], si[N2d];
    #pragma unroll
    for (int j = 0; j < N2d; ++j) { sr[j] = 0.f; si[j] = 0.f; }
    float sdt = 0.f;
    const int lbase = c * CLEN;
    if (fast) {
        #pragma unroll 2
        for (int k = 0; k < CLEN; ++k) {
            float2 d = du[(lbase + k) * Hd + h];
            float dtv = d.x, us = d.y;
            sdt += dtv;
            float er = __expf(dtv * Are0);
            float s0, c0, sd, cd;
            __sincosf(dtv * Aim0, &s0, &c0);
            __sincosf(dtv * dA, &sd, &cd);
            float ar = er * c0, ai = er * s0;
            #pragma unroll
            for (int j = 0; j < N2d; ++j) {
                float gr = fmaf(ar, us, -us);
                float gi = ai * us;
                float nr = fmaf(ar, sr[j], fmaf(-ai, si[j], fmaf(gr, BAr[j], -gi * BAi[j])));
                float ni = fmaf(ar, si[j], fmaf( ai, sr[j], fmaf(gr, BAi[j],  gi * BAr[j])));
                sr[j] = nr; si[j] = ni;
                if (j < N2d - 1) {
                    float tr = fmaf(ar, cd, -ai * sd);
                    ai = fmaf(ai, cd, ar * sd);
                    ar = tr;
                }
            }
        }
        // P_j = exp(A_j * sdt) via rotation chain
        float er = __expf(sdt * Are0);
        float s0, c0, sd, cd;
        __sincosf(sdt * Aim0, &s0, &c0);
        __sincosf(sdt * dA, &sd, &cd);
        float pr = er * c0, pi = er * s0;
        #pragma unroll
        for (int j = 0; j < N2d; ++j) {
            PS[c * NCH + j * Hd + h] = make_float4(pr, pi, sr[j], si[j]);
            float tr = fmaf(pr, cd, -pi * sd);
            pi = fmaf(pi, cd, pr * sd);
            pr = tr;
        }
    } else {
        for (int k = 0; k < CLEN; ++k) {
            float2 d = du[(lbase + k) * Hd + h];
            float dtv = d.x, us = d.y;
            sdt += dtv;
            #pragma unroll
            for (int j = 0; j < N2d; ++j) {
                int hn = h * N2d + j;
                float er = __expf(dtv * -__expf(A_log[hn]));
                float s, cc;
                __sincosf(dtv * A_im[hn], &s, &cc);
                float ar = er * cc, ai = er * s;
                float gr = fmaf(ar, us, -us);
                float gi = ai * us;
                float nr = fmaf(ar, sr[j], fmaf(-ai, si[j], fmaf(gr, BAr[j], -gi * BAi[j])));
                float ni = fmaf(ar, si[j], fmaf( ai, sr[j], fmaf(gr, BAi[j],  gi * BAr[j])));
                sr[j] = nr; si[j] = ni;
            }
        }
        #pragma unroll
        for (int j = 0; j < N2d; ++j) {
            int hn = h * N2d + j;
            float er = __expf(sdt * -__expf(A_log[hn]));
            float s, cc;
            __sincosf(sdt * A_im[hn], &s, &cc);
            PS[c * NCH + j * Hd + h] = make_float4(er * cc, er * s, sr[j], si[j]);
        }
    }
}

// ---------------------------------------------------------------------------
// Kernel 3 (phase 2): serial combine over 256 chunks -> init state per chunk.
// 8192 threads; loads batched 16 per vmcnt window to hide latency.
// ---------------------------------------------------------------------------
__global__ __launch_bounds__(256) void k_prefix(const float4* __restrict__ PS,
                                                float2* __restrict__ Ibuf) {
    int idx = blockIdx.x * 256 + threadIdx.x;  // 0..8191 = n*512+h
    float hr = 0.f, hi = 0.f;
    for (int b = 0; b < NCHUNK / 16; ++b) {
        float4 tp[16];
        #pragma unroll
        for (int i = 0; i < 16; ++i) tp[i] = PS[(b * 16 + i) * NCH + idx];
        #pragma unroll
        for (int i = 0; i < 16; ++i) {
            Ibuf[(b * 16 + i) * NCH + idx] = make_float2(hr, hi);
            float nr = fmaf(tp[i].x, hr, fmaf(-tp[i].y, hi, tp[i].z));
            float ni = fmaf(tp[i].x, hi, fmaf( tp[i].y, hr, tp[i].w));
            hr = nr; hi = ni;
        }
    }
}

// ---------------------------------------------------------------------------
// Kernel 4 (phase 3): re-scan with correct init; full y in-register, no
// shuffles; coalesced scalar store per step.
// ---------------------------------------------------------------------------
__global__ __launch_bounds__(256) void k_scan(const float2* __restrict__ du,
        const float* __restrict__ A_log, const float* __restrict__ A_im,
        const float* __restrict__ B_param, const float* __restrict__ C_param,
        const float* __restrict__ Dp, const float2* __restrict__ Ibuf,
        float* __restrict__ out) {
    const int h = blockIdx.y * 256 + threadIdx.x;
    const int c = blockIdx.x;
    float Are0, Aim0, dA, BAr[N2d], BAi[N2d];
    const bool fast = setup_h(A_log, A_im, B_param, h, Are0, Aim0, dA, BAr, BAi);
    float Cre[N2d], Cim[N2d];
    #pragma unroll
    for (int j = 0; j < N2d; ++j) {
        Cre[j] = C_param[2 * (h * N2d + j)];
        Cim[j] = C_param[2 * (h * N2d + j) + 1];
    }
    const float Dv = Dp[h];
    float sr[N2d], si[N2d];
    #pragma unroll
    for (int j = 0; j < N2d; ++j) {
        float2 h0 = Ibuf[c * NCH + j * Hd + h];
        sr[j] = h0.x; si[j] = h0.y;
    }
    const int lbase = c * CLEN;
    if (fast) {
        #pragma unroll 2
        for (int k = 0; k < CLEN; ++k) {
            int l = lbase + k;
            float2 d = du[l * Hd + h];
            float dtv = d.x, us = d.y;
            float er = __expf(dtv * Are0);
            float s0, c0, sd, cd;
            __sincosf(dtv * Aim0, &s0, &c0);
            __sincosf(dtv * dA, &sd, &cd);
            float ar = er * c0, ai = er * s0;
            float yv = 0.f;
            #pragma unroll
            for (int j = 0; j < N2d; ++j) {
                float gr = fmaf(ar, us, -us);
                float gi = ai * us;
                float nr = fmaf(ar, sr[j], fmaf(-ai, si[j], fmaf(gr, BAr[j], -gi * BAi[j])));
                float ni = fmaf(ar, si[j], fmaf( ai, sr[j], fmaf(gr, BAi[j],  gi * BAr[j])));
                sr[j] = nr; si[j] = ni;
                yv = fmaf(nr, Cre[j], fmaf(-ni, Cim[j], yv));
                if (j < N2d - 1) {
                    float tr = fmaf(ar, cd, -ai * sd);
                    ai = fmaf(ai, cd, ar * sd);
                    ar = tr;
                }
            }
            out[l * Hd + h] = fmaf(dtv * us, Dv, yv);
        }
    } else {
        for (int k = 0; k < CLEN; ++k) {
            int l = lbase + k;
            float2 d = du[l * Hd + h];
            float dtv = d.x, us = d.y;
            float yv = 0.f;
            #pragma unroll
            for (int j = 0; j < N2d; ++j) {
                int hn = h * N2d + j;
                float er = __expf(dtv * -__expf(A_log[hn]));
                float s, cc;
                __sincosf(dtv * A_im[hn], &s, &cc);
                float ar = er * cc, ai = er * s;
                float gr = fmaf(ar, us, -us);
                float gi = ai * us;
                float nr = fmaf(ar, sr[j], fmaf(-ai, si[j], fmaf(gr, BAr[j], -gi * BAi[j])));
                float ni = fmaf(ar, si[j], fmaf( ai, sr[j], fmaf(gr, BAi[j],  gi * BAr[j])));
                sr[j] = nr; si[j] = ni;
                yv = fmaf(nr, Cre[j], fmaf(-ni, Cim[j], yv));
            }
            out[l * Hd + h] = fmaf(dtv * us, Dv, yv);
        }
    }
}

extern "C" void kernel_launch(void* const* d_in, const int* in_sizes, int n_in,
                              void* d_out, int out_size, void* d_ws, size_t ws_size,
                              hipStream_t stream) {
    const float* u        = (const float*)d_in[0];
    const float* A_log    = (const float*)d_in[1];
    const float* A_im     = (const float*)d_in[2];
    const float* B_param  = (const float*)d_in[3];
    const float* C_param  = (const float*)d_in[4];
    const float* Dp       = (const float*)d_in[5];
    const float* dt_w     = (const float*)d_in[6];
    const float* dt_b     = (const float*)d_in[7];
    const float* xproj_w  = (const float*)d_in[8];

    // ws: du[L*H f2] | PS[NCHUNK*NCH f4] | I[NCHUNK*NCH f2] | dt_wT[R*H f]
    float2* du   = (float2*)d_ws;
    float4* PS   = (float4*)(du + (size_t)Ld * Hd);
    float2* Ibuf = (float2*)(PS + (size_t)NCHUNK * NCH);
    float*  dt_wT = (float*)(Ibuf + (size_t)NCHUNK * NCH);
    float*  out  = (float*)d_out;

    k_tw<<<(Rd * Hd) / 256, 256, 0, stream>>>(dt_w, dt_wT);
    k_dt<<<Ld / 8, 256, 0, stream>>>(u, xproj_w, dt_wT, dt_b, du);
    dim3 g2(NCHUNK, Hd / 256);
    k_chunk<<<g2, 256, 0, stream>>>(du, A_log, A_im, B_param, PS);
    k_prefix<<<NCH / 256, 256, 0, stream>>>(PS, Ibuf);
    k_scan<<<g2, 256, 0, stream>>>(du, A_log, A_im, B_param, C_param, Dp, Ibuf, out);
}

// Round 7
// 166.434 us; speedup vs baseline: 1.0253x; 1.0081x over previous
//
#include <hip/hip_runtime.h>

#define Hd 512
#define N2d 16
#define Rd 32
#define Ld 4096
#define NCHUNK 256
#define CLEN (Ld / NCHUNK)   // 16
#define NCH (Hd * N2d)       // 8192 chains

// ---------------------------------------------------------------------------
// Kernel 0: transpose dt_w[H][R] -> dt_wT[R][H].
// ---------------------------------------------------------------------------
__global__ __launch_bounds__(256) void k_tw(const float* __restrict__ dt_w,
                                            float* __restrict__ dt_wT) {
    int idx = blockIdx.x * 256 + threadIdx.x;
    int r = idx >> 9;
    int h = idx & 511;
    dt_wT[idx] = dt_w[h * Rd + r];
}

// ---------------------------------------------------------------------------
// Kernel 1: dt = softplus(u@xprojT@dtwT + b); writes SoA planes
// dtp[l][h] = dt, usp[l][h] = u/dt (stride-2048B per l => immediate offsets
// in the scan kernels).
// ---------------------------------------------------------------------------
__global__ __launch_bounds__(256) void k_dt(const float* __restrict__ u,
                                            const float* __restrict__ xproj_w,
                                            const float* __restrict__ dt_wT,
                                            const float* __restrict__ dt_b,
                                            float* __restrict__ dtp,
                                            float* __restrict__ usp) {
    __shared__ float u_s[8][Hd];
    __shared__ float dtu_s[8][Rd];
    const int t = threadIdx.x;
    const int l0 = blockIdx.x * 8;

    #pragma unroll
    for (int i = 0; i < 16; ++i) {
        int idx = t + i * 256;
        ((float*)u_s)[idx] = u[l0 * Hd + idx];
    }
    __syncthreads();

    const int r = t >> 3;
    const int j = t & 7;
    float part[8];
    #pragma unroll
    for (int l = 0; l < 8; ++l) part[l] = 0.f;
    for (int k = 0; k < 64; ++k) {
        float w = xproj_w[r * Hd + k * 8 + j];
        #pragma unroll
        for (int l = 0; l < 8; ++l) part[l] = fmaf(u_s[l][k * 8 + j], w, part[l]);
    }
    #pragma unroll
    for (int off = 1; off < 8; off <<= 1) {
        #pragma unroll
        for (int l = 0; l < 8; ++l) part[l] += __shfl_xor(part[l], off);
    }
    if (j == 0) {
        #pragma unroll
        for (int l = 0; l < 8; ++l) dtu_s[l][r] = part[l];
    }
    __syncthreads();

    #pragma unroll
    for (int hb = 0; hb < 2; ++hb) {
        int h = hb * 256 + t;
        float bias = dt_b[h];
        float acc[8];
        #pragma unroll
        for (int l = 0; l < 8; ++l) acc[l] = bias;
        for (int rr = 0; rr < Rd; ++rr) {
            float w = dt_wT[rr * Hd + h];
            #pragma unroll
            for (int l = 0; l < 8; ++l) acc[l] = fmaf(dtu_s[l][rr], w, acc[l]);
        }
        #pragma unroll
        for (int l = 0; l < 8; ++l) {
            float x = acc[l];
            float sp = fmaxf(x, 0.f) + log1pf(__expf(-fabsf(x)));  // softplus
            float uv = u_s[l][h];
            float us = uv * __builtin_amdgcn_rcpf(fmaxf(sp, 1e-30f));
            dtp[(l0 + l) * Hd + h] = sp;
            usp[(l0 + l) * Hd + h] = us;
        }
    }
}

// ---------------------------------------------------------------------------
// Per-thread setup for one h, all 16 n. Returns mode:
//  2 = Are uniform, Aim = j*dA exactly (Aim0==0)  -> fastz path (3 trans/step)
//  1 = Are uniform, Aim arithmetic                -> fast path  (5 trans/step)
//  0 = general                                    -> slow path
// BA[j] = Bc_j / A_j (ZOH division folded into a constant).
// ---------------------------------------------------------------------------
__device__ __forceinline__ int setup_h(const float* __restrict__ A_log,
        const float* __restrict__ A_im, const float* __restrict__ B_param,
        int h, float& Are0, float& Aim0, float& dA,
        float* __restrict__ BAr, float* __restrict__ BAi) {
    const int hb = h * N2d;
    Are0 = -__expf(A_log[hb]);
    Aim0 = A_im[hb];
    dA = A_im[hb + 1] - Aim0;
    bool ok = true;
    #pragma unroll
    for (int j = 0; j < N2d; ++j) {
        int hn = hb + j;
        float Ar = -__expf(A_log[hn]);
        float Ai = A_im[hn];
        ok = ok && (Ar == Are0) && (Ai == fmaf((float)j, dA, Aim0));
        float Br = B_param[2 * hn];
        float Bi = B_param[2 * hn + 1];
        float inv = __builtin_amdgcn_rcpf(Ar * Ar + Ai * Ai);
        BAr[j] = (Br * Ar + Bi * Ai) * inv;
        BAi[j] = (Bi * Ar - Br * Ai) * inv;
    }
    if (!ok) return 0;
    return (Aim0 == 0.f) ? 2 : 1;
}

// ---------------------------------------------------------------------------
// Kernel 2 (phase 1): chunk-local scan (h0=0), 16 n per thread, no shuffles.
// Emits PS[c][n][h] = (P_re, P_im, S_re, S_im), P = exp(A*sum_dt) exactly.
// Grid (NCHUNK, Hd/256), block 256.
// ---------------------------------------------------------------------------
__global__ __launch_bounds__(256) void k_chunk(const float* __restrict__ dtp,
        const float* __restrict__ usp,
        const float* __restrict__ A_log, const float* __restrict__ A_im,
        const float* __restrict__ B_param, float4* __restrict__ PS) {
    const int h = blockIdx.y * 256 + threadIdx.x;
    const int c = blockIdx.x;
    float Are0, Aim0, dA, BAr[N2d], BAi[N2d];
    const int mode = setup_h(A_log, A_im, B_param, h, Are0, Aim0, dA, BAr, BAi);
    float sr[N2d], si[N2d];
    #pragma unroll
    for (int j = 0; j < N2d; ++j) { sr[j] = 0.f; si[j] = 0.f; }
    float sdt = 0.f;
    const float* dp = dtp + (size_t)c * CLEN * Hd + h;
    const float* up = usp + (size_t)c * CLEN * Hd + h;
    if (mode == 2) {
        #pragma unroll 4
        for (int k = 0; k < CLEN; ++k) {
            float dtv = dp[k * Hd];
            float us  = up[k * Hd];
            sdt += dtv;
            float er = __expf(dtv * Are0);
            float sd, cd;
            __sincosf(dtv * dA, &sd, &cd);
            // j = 0 : a = (er, 0)
            {
                float gr = fmaf(er, us, -us);
                float nr = fmaf(er, sr[0], gr * BAr[0]);
                float ni = fmaf(er, si[0], gr * BAi[0]);
                sr[0] = nr; si[0] = ni;
            }
            float ar = er * cd, ai = er * sd;
            #pragma unroll
            for (int j = 1; j < N2d; ++j) {
                float gr = fmaf(ar, us, -us);
                float gi = ai * us;
                float nr = fmaf(ar, sr[j], fmaf(-ai, si[j], fmaf(gr, BAr[j], -gi * BAi[j])));
                float ni = fmaf(ar, si[j], fmaf( ai, sr[j], fmaf(gr, BAi[j],  gi * BAr[j])));
                sr[j] = nr; si[j] = ni;
                if (j < N2d - 1) {
                    float tr = fmaf(ar, cd, -ai * sd);
                    ai = fmaf(ai, cd, ar * sd);
                    ar = tr;
                }
            }
        }
        float er = __expf(sdt * Are0);
        float sd, cd;
        __sincosf(sdt * dA, &sd, &cd);
        float pr = er, pi = 0.f;
        #pragma unroll
        for (int j = 0; j < N2d; ++j) {
            PS[c * NCH + j * Hd + h] = make_float4(pr, pi, sr[j], si[j]);
            float tr = fmaf(pr, cd, -pi * sd);
            pi = fmaf(pi, cd, pr * sd);
            pr = tr;
        }
    } else if (mode == 1) {
        #pragma unroll 2
        for (int k = 0; k < CLEN; ++k) {
            float dtv = dp[k * Hd];
            float us  = up[k * Hd];
            sdt += dtv;
            float er = __expf(dtv * Are0);
            float s0, c0, sd, cd;
            __sincosf(dtv * Aim0, &s0, &c0);
            __sincosf(dtv * dA, &sd, &cd);
            float ar = er * c0, ai = er * s0;
            #pragma unroll
            for (int j = 0; j < N2d; ++j) {
                float gr = fmaf(ar, us, -us);
                float gi = ai * us;
                float nr = fmaf(ar, sr[j], fmaf(-ai, si[j], fmaf(gr, BAr[j], -gi * BAi[j])));
                float ni = fmaf(ar, si[j], fmaf( ai, sr[j], fmaf(gr, BAi[j],  gi * BAr[j])));
                sr[j] = nr; si[j] = ni;
                if (j < N2d - 1) {
                    float tr = fmaf(ar, cd, -ai * sd);
                    ai = fmaf(ai, cd, ar * sd);
                    ar = tr;
                }
            }
        }
        float er = __expf(sdt * Are0);
        float s0, c0, sd, cd;
        __sincosf(sdt * Aim0, &s0, &c0);
        __sincosf(sdt * dA, &sd, &cd);
        float pr = er * c0, pi = er * s0;
        #pragma unroll
        for (int j = 0; j < N2d; ++j) {
            PS[c * NCH + j * Hd + h] = make_float4(pr, pi, sr[j], si[j]);
            float tr = fmaf(pr, cd, -pi * sd);
            pi = fmaf(pi, cd, pr * sd);
            pr = tr;
        }
    } else {
        for (int k = 0; k < CLEN; ++k) {
            float dtv = dp[k * Hd];
            float us  = up[k * Hd];
            sdt += dtv;
            #pragma unroll
            for (int j = 0; j < N2d; ++j) {
                int hn = h * N2d + j;
                float er = __expf(dtv * -__expf(A_log[hn]));
                float s, cc;
                __sincosf(dtv * A_im[hn], &s, &cc);
                float ar = er * cc, ai = er * s;
                float gr = fmaf(ar, us, -us);
                float gi = ai * us;
                float nr = fmaf(ar, sr[j], fmaf(-ai, si[j], fmaf(gr, BAr[j], -gi * BAi[j])));
                float ni = fmaf(ar, si[j], fmaf( ai, sr[j], fmaf(gr, BAi[j],  gi * BAr[j])));
                sr[j] = nr; si[j] = ni;
            }
        }
        #pragma unroll
        for (int j = 0; j < N2d; ++j) {
            int hn = h * N2d + j;
            float er = __expf(sdt * -__expf(A_log[hn]));
            float s, cc;
            __sincosf(sdt * A_im[hn], &s, &cc);
            PS[c * NCH + j * Hd + h] = make_float4(er * cc, er * s, sr[j], si[j]);
        }
    }
}

// ---------------------------------------------------------------------------
// Kernel 3 (phase 2): serial combine over 256 chunks -> init state per chunk.
// 8192 threads; loads batched 16 per vmcnt window.
// ---------------------------------------------------------------------------
__global__ __launch_bounds__(256) void k_prefix(const float4* __restrict__ PS,
                                                float2* __restrict__ Ibuf) {
    int idx = blockIdx.x * 256 + threadIdx.x;  // 0..8191 = n*512+h
    float hr = 0.f, hi = 0.f;
    for (int b = 0; b < NCHUNK / 16; ++b) {
        float4 tp[16];
        #pragma unroll
        for (int i = 0; i < 16; ++i) tp[i] = PS[(b * 16 + i) * NCH + idx];
        #pragma unroll
        for (int i = 0; i < 16; ++i) {
            Ibuf[(b * 16 + i) * NCH + idx] = make_float2(hr, hi);
            float nr = fmaf(tp[i].x, hr, fmaf(-tp[i].y, hi, tp[i].z));
            float ni = fmaf(tp[i].x, hi, fmaf( tp[i].y, hr, tp[i].w));
            hr = nr; hi = ni;
        }
    }
}

// ---------------------------------------------------------------------------
// Kernel 4 (phase 3): re-scan with correct init; y fully in-register.
// ---------------------------------------------------------------------------
__global__ __launch_bounds__(256) void k_scan(const float* __restrict__ dtp,
        const float* __restrict__ usp,
        const float* __restrict__ A_log, const float* __restrict__ A_im,
        const float* __restrict__ B_param, const float* __restrict__ C_param,
        const float* __restrict__ Dp, const float2* __restrict__ Ibuf,
        float* __restrict__ out) {
    const int h = blockIdx.y * 256 + threadIdx.x;
    const int c = blockIdx.x;
    float Are0, Aim0, dA, BAr[N2d], BAi[N2d];
    const int mode = setup_h(A_log, A_im, B_param, h, Are0, Aim0, dA, BAr, BAi);
    float Cre[N2d], Cim[N2d];
    #pragma unroll
    for (int j = 0; j < N2d; ++j) {
        Cre[j] = C_param[2 * (h * N2d + j)];
        Cim[j] = C_param[2 * (h * N2d + j) + 1];
    }
    const float Dv = Dp[h];
    float sr[N2d], si[N2d];
    #pragma unroll
    for (int j = 0; j < N2d; ++j) {
        float2 h0 = Ibuf[c * NCH + j * Hd + h];
        sr[j] = h0.x; si[j] = h0.y;
    }
    const float* dp = dtp + (size_t)c * CLEN * Hd + h;
    const float* up = usp + (size_t)c * CLEN * Hd + h;
    float* op = out + (size_t)c * CLEN * Hd + h;
    if (mode == 2) {
        #pragma unroll 4
        for (int k = 0; k < CLEN; ++k) {
            float dtv = dp[k * Hd];
            float us  = up[k * Hd];
            float er = __expf(dtv * Are0);
            float sd, cd;
            __sincosf(dtv * dA, &sd, &cd);
            float yv;
            {
                float gr = fmaf(er, us, -us);
                float nr = fmaf(er, sr[0], gr * BAr[0]);
                float ni = fmaf(er, si[0], gr * BAi[0]);
                sr[0] = nr; si[0] = ni;
                yv = fmaf(nr, Cre[0], -ni * Cim[0]);
            }
            float ar = er * cd, ai = er * sd;
            #pragma unroll
            for (int j = 1; j < N2d; ++j) {
                float gr = fmaf(ar, us, -us);
                float gi = ai * us;
                float nr = fmaf(ar, sr[j], fmaf(-ai, si[j], fmaf(gr, BAr[j], -gi * BAi[j])));
                float ni = fmaf(ar, si[j], fmaf( ai, sr[j], fmaf(gr, BAi[j],  gi * BAr[j])));
                sr[j] = nr; si[j] = ni;
                yv = fmaf(nr, Cre[j], fmaf(-ni, Cim[j], yv));
                if (j < N2d - 1) {
                    float tr = fmaf(ar, cd, -ai * sd);
                    ai = fmaf(ai, cd, ar * sd);
                    ar = tr;
                }
            }
            op[k * Hd] = fmaf(dtv * us, Dv, yv);
        }
    } else if (mode == 1) {
        #pragma unroll 2
        for (int k = 0; k < CLEN; ++k) {
            float dtv = dp[k * Hd];
            float us  = up[k * Hd];
            float er = __expf(dtv * Are0);
            float s0, c0, sd, cd;
            __sincosf(dtv * Aim0, &s0, &c0);
            __sincosf(dtv * dA, &sd, &cd);
            float ar = er * c0, ai = er * s0;
            float yv = 0.f;
            #pragma unroll
            for (int j = 0; j < N2d; ++j) {
                float gr = fmaf(ar, us, -us);
                float gi = ai * us;
                float nr = fmaf(ar, sr[j], fmaf(-ai, si[j], fmaf(gr, BAr[j], -gi * BAi[j])));
                float ni = fmaf(ar, si[j], fmaf( ai, sr[j], fmaf(gr, BAi[j],  gi * BAr[j])));
                sr[j] = nr; si[j] = ni;
                yv = fmaf(nr, Cre[j], fmaf(-ni, Cim[j], yv));
                if (j < N2d - 1) {
                    float tr = fmaf(ar, cd, -ai * sd);
                    ai = fmaf(ai, cd, ar * sd);
                    ar = tr;
                }
            }
            op[k * Hd] = fmaf(dtv * us, Dv, yv);
        }
    } else {
        for (int k = 0; k < CLEN; ++k) {
            float dtv = dp[k * Hd];
            float us  = up[k * Hd];
            float yv = 0.f;
            #pragma unroll
            for (int j = 0; j < N2d; ++j) {
                int hn = h * N2d + j;
                float er = __expf(dtv * -__expf(A_log[hn]));
                float s, cc;
                __sincosf(dtv * A_im[hn], &s, &cc);
                float ar = er * cc, ai = er * s;
                float gr = fmaf(ar, us, -us);
                float gi = ai * us;
                float nr = fmaf(ar, sr[j], fmaf(-ai, si[j], fmaf(gr, BAr[j], -gi * BAi[j])));
                float ni = fmaf(ar, si[j], fmaf( ai, sr[j], fmaf(gr, BAi[j],  gi * BAr[j])));
                sr[j] = nr; si[j] = ni;
                yv = fmaf(nr, Cre[j], fmaf(-ni, Cim[j], yv));
            }
            op[k * Hd] = fmaf(dtv * us, Dv, yv);
        }
    }
}

extern "C" void kernel_launch(void* const* d_in, const int* in_sizes, int n_in,
                              void* d_out, int out_size, void* d_ws, size_t ws_size,
                              hipStream_t stream) {
    const float* u        = (const float*)d_in[0];
    const float* A_log    = (const float*)d_in[1];
    const float* A_im     = (const float*)d_in[2];
    const float* B_param  = (const float*)d_in[3];
    const float* C_param  = (const float*)d_in[4];
    const float* Dp       = (const float*)d_in[5];
    const float* dt_w     = (const float*)d_in[6];
    const float* dt_b     = (const float*)d_in[7];
    const float* xproj_w  = (const float*)d_in[8];

    // ws: dtp[L*H] | usp[L*H] | PS[NCHUNK*NCH f4] | I[NCHUNK*NCH f2] | dt_wT
    float*  dtp  = (float*)d_ws;
    float*  usp  = dtp + (size_t)Ld * Hd;
    float4* PS   = (float4*)(usp + (size_t)Ld * Hd);
    float2* Ibuf = (float2*)(PS + (size_t)NCHUNK * NCH);
    float*  dt_wT = (float*)(Ibuf + (size_t)NCHUNK * NCH);
    float*  out  = (float*)d_out;

    k_tw<<<(Rd * Hd) / 256, 256, 0, stream>>>(dt_w, dt_wT);
    k_dt<<<Ld / 8, 256, 0, stream>>>(u, xproj_w, dt_wT, dt_b, dtp, usp);
    dim3 g2(NCHUNK, Hd / 256);
    k_chunk<<<g2, 256, 0, stream>>>(dtp, usp, A_log, A_im, B_param, PS);
    k_prefix<<<NCH / 256, 256, 0, stream>>>(PS, Ibuf);
    k_scan<<<g2, 256, 0, stream>>>(dtp, usp, A_log, A_im, B_param, C_param,
                                   Dp, Ibuf, out);
}

// Round 8
// 160.389 us; speedup vs baseline: 1.0639x; 1.0377x over previous
//
#include <hip/hip_runtime.h>

#define Hd 512
#define N2d 16
#define Rd 32
#define Ld 4096
#define NCHUNK 256
#define CLEN (Ld / NCHUNK)   // 16
#define NCH (Hd * N2d)       // 8192 chains

// ---------------------------------------------------------------------------
// Kernel 0: transpose dt_w[H][R] -> dt_wT[R][H].
// ---------------------------------------------------------------------------
__global__ __launch_bounds__(256) void k_tw(const float* __restrict__ dt_w,
                                            float* __restrict__ dt_wT) {
    int idx = blockIdx.x * 256 + threadIdx.x;
    int r = idx >> 9;
    int h = idx & 511;
    dt_wT[idx] = dt_w[h * Rd + r];
}

// ---------------------------------------------------------------------------
// Kernel 1a: dt_u[l][r] = sum_h u[l][h] * xproj_w[r][h].
// 1024 blocks x 256 threads; 4 l per block; (r, j) = (t>>3, t&7).
// ---------------------------------------------------------------------------
__global__ __launch_bounds__(256) void k_dt1(const float* __restrict__ u,
                                             const float* __restrict__ xproj_w,
                                             float* __restrict__ dt_u) {
    __shared__ float u_s[4][Hd];   // 8 KB
    const int t = threadIdx.x;
    const int l0 = blockIdx.x * 4;
    #pragma unroll
    for (int i = 0; i < 8; ++i) {
        int idx = t + i * 256;
        ((float*)u_s)[idx] = u[l0 * Hd + idx];
    }
    __syncthreads();
    const int r = t >> 3;
    const int j = t & 7;
    float part[4] = {0.f, 0.f, 0.f, 0.f};
    for (int k = 0; k < 64; ++k) {
        float w = xproj_w[r * Hd + k * 8 + j];
        #pragma unroll
        for (int l = 0; l < 4; ++l) part[l] = fmaf(u_s[l][k * 8 + j], w, part[l]);
    }
    #pragma unroll
    for (int off = 1; off < 8; off <<= 1) {
        #pragma unroll
        for (int l = 0; l < 4; ++l) part[l] += __shfl_xor(part[l], off);
    }
    if (j == 0) {
        #pragma unroll
        for (int l = 0; l < 4; ++l) dt_u[(l0 + l) * Rd + r] = part[l];
    }
}

// ---------------------------------------------------------------------------
// Kernel 1b: dt = softplus(dt_u @ dt_wT + b); writes dtp = dt, usp = u/dt.
// Grid (Ld/4, Hd/256) = 2048 blocks; thread = one h, 4 l.
// ---------------------------------------------------------------------------
__global__ __launch_bounds__(256) void k_dt2(const float* __restrict__ u,
                                             const float* __restrict__ dt_u,
                                             const float* __restrict__ dt_wT,
                                             const float* __restrict__ dt_b,
                                             float* __restrict__ dtp,
                                             float* __restrict__ usp) {
    __shared__ float du_s[4][Rd];  // 512 B
    const int t = threadIdx.x;
    const int l0 = blockIdx.x * 4;
    const int h = blockIdx.y * 256 + t;
    if (t < 4 * Rd) ((float*)du_s)[t] = dt_u[l0 * Rd + t];
    __syncthreads();
    float bias = dt_b[h];
    float acc[4] = {bias, bias, bias, bias};
    for (int r = 0; r < Rd; ++r) {
        float w = dt_wT[r * Hd + h];           // coalesced
        #pragma unroll
        for (int l = 0; l < 4; ++l) acc[l] = fmaf(du_s[l][r], w, acc[l]);
    }
    #pragma unroll
    for (int l = 0; l < 4; ++l) {
        float x = acc[l];
        float e = __expf(-fabsf(x));
        float sp = fmaxf(x, 0.f) + __logf(1.f + e);   // fast softplus
        float uv = u[(l0 + l) * Hd + h];
        float us = uv * __builtin_amdgcn_rcpf(fmaxf(sp, 1e-30f));
        dtp[(l0 + l) * Hd + h] = sp;
        usp[(l0 + l) * Hd + h] = us;
    }
}

// ---------------------------------------------------------------------------
// Per-thread setup for one h, all 16 n. Returns mode:
//  2 = Are uniform, Aim = j*dA exactly (Aim0==0)  -> fastz path (3 trans/step)
//  1 = Are uniform, Aim arithmetic                -> fast path  (5 trans/step)
//  0 = general                                    -> slow path
// BA[j] = Bc_j / A_j (ZOH division folded into a constant).
// ---------------------------------------------------------------------------
__device__ __forceinline__ int setup_h(const float* __restrict__ A_log,
        const float* __restrict__ A_im, const float* __restrict__ B_param,
        int h, float& Are0, float& Aim0, float& dA,
        float* __restrict__ BAr, float* __restrict__ BAi) {
    const int hb = h * N2d;
    Are0 = -__expf(A_log[hb]);
    Aim0 = A_im[hb];
    dA = A_im[hb + 1] - Aim0;
    bool ok = true;
    #pragma unroll
    for (int j = 0; j < N2d; ++j) {
        int hn = hb + j;
        float Ar = -__expf(A_log[hn]);
        float Ai = A_im[hn];
        ok = ok && (Ar == Are0) && (Ai == fmaf((float)j, dA, Aim0));
        float Br = B_param[2 * hn];
        float Bi = B_param[2 * hn + 1];
        float inv = __builtin_amdgcn_rcpf(Ar * Ar + Ai * Ai);
        BAr[j] = (Br * Ar + Bi * Ai) * inv;
        BAi[j] = (Bi * Ar - Br * Ai) * inv;
    }
    if (!ok) return 0;
    return (Aim0 == 0.f) ? 2 : 1;
}

// ---------------------------------------------------------------------------
// Kernel 2 (phase 1): chunk-local scan (h0=0), 16 n per thread, no shuffles.
// Emits PS[c][n][h] = (P_re, P_im, S_re, S_im), P = exp(A*sum_dt) exactly.
// Grid (NCHUNK, Hd/256), block 256.
// ---------------------------------------------------------------------------
__global__ __launch_bounds__(256) void k_chunk(const float* __restrict__ dtp,
        const float* __restrict__ usp,
        const float* __restrict__ A_log, const float* __restrict__ A_im,
        const float* __restrict__ B_param, float4* __restrict__ PS) {
    const int h = blockIdx.y * 256 + threadIdx.x;
    const int c = blockIdx.x;
    float Are0, Aim0, dA, BAr[N2d], BAi[N2d];
    const int mode = setup_h(A_log, A_im, B_param, h, Are0, Aim0, dA, BAr, BAi);
    float sr[N2d], si[N2d];
    #pragma unroll
    for (int j = 0; j < N2d; ++j) { sr[j] = 0.f; si[j] = 0.f; }
    float sdt = 0.f;
    const float* dp = dtp + (size_t)c * CLEN * Hd + h;
    const float* up = usp + (size_t)c * CLEN * Hd + h;
    if (mode == 2) {
        #pragma unroll 4
        for (int k = 0; k < CLEN; ++k) {
            float dtv = dp[k * Hd];
            float us  = up[k * Hd];
            sdt += dtv;
            float er = __expf(dtv * Are0);
            float sd, cd;
            __sincosf(dtv * dA, &sd, &cd);
            {
                float gr = fmaf(er, us, -us);
                float nr = fmaf(er, sr[0], gr * BAr[0]);
                float ni = fmaf(er, si[0], gr * BAi[0]);
                sr[0] = nr; si[0] = ni;
            }
            float ar = er * cd, ai = er * sd;
            #pragma unroll
            for (int j = 1; j < N2d; ++j) {
                float gr = fmaf(ar, us, -us);
                float gi = ai * us;
                float nr = fmaf(ar, sr[j], fmaf(-ai, si[j], fmaf(gr, BAr[j], -gi * BAi[j])));
                float ni = fmaf(ar, si[j], fmaf( ai, sr[j], fmaf(gr, BAi[j],  gi * BAr[j])));
                sr[j] = nr; si[j] = ni;
                if (j < N2d - 1) {
                    float tr = fmaf(ar, cd, -ai * sd);
                    ai = fmaf(ai, cd, ar * sd);
                    ar = tr;
                }
            }
        }
        float er = __expf(sdt * Are0);
        float sd, cd;
        __sincosf(sdt * dA, &sd, &cd);
        float pr = er, pi = 0.f;
        #pragma unroll
        for (int j = 0; j < N2d; ++j) {
            PS[c * NCH + j * Hd + h] = make_float4(pr, pi, sr[j], si[j]);
            float tr = fmaf(pr, cd, -pi * sd);
            pi = fmaf(pi, cd, pr * sd);
            pr = tr;
        }
    } else if (mode == 1) {
        #pragma unroll 2
        for (int k = 0; k < CLEN; ++k) {
            float dtv = dp[k * Hd];
            float us  = up[k * Hd];
            sdt += dtv;
            float er = __expf(dtv * Are0);
            float s0, c0, sd, cd;
            __sincosf(dtv * Aim0, &s0, &c0);
            __sincosf(dtv * dA, &sd, &cd);
            float ar = er * c0, ai = er * s0;
            #pragma unroll
            for (int j = 0; j < N2d; ++j) {
                float gr = fmaf(ar, us, -us);
                float gi = ai * us;
                float nr = fmaf(ar, sr[j], fmaf(-ai, si[j], fmaf(gr, BAr[j], -gi * BAi[j])));
                float ni = fmaf(ar, si[j], fmaf( ai, sr[j], fmaf(gr, BAi[j],  gi * BAr[j])));
                sr[j] = nr; si[j] = ni;
                if (j < N2d - 1) {
                    float tr = fmaf(ar, cd, -ai * sd);
                    ai = fmaf(ai, cd, ar * sd);
                    ar = tr;
                }
            }
        }
        float er = __expf(sdt * Are0);
        float s0, c0, sd, cd;
        __sincosf(sdt * Aim0, &s0, &c0);
        __sincosf(sdt * dA, &sd, &cd);
        float pr = er * c0, pi = er * s0;
        #pragma unroll
        for (int j = 0; j < N2d; ++j) {
            PS[c * NCH + j * Hd + h] = make_float4(pr, pi, sr[j], si[j]);
            float tr = fmaf(pr, cd, -pi * sd);
            pi = fmaf(pi, cd, pr * sd);
            pr = tr;
        }
    } else {
        for (int k = 0; k < CLEN; ++k) {
            float dtv = dp[k * Hd];
            float us  = up[k * Hd];
            sdt += dtv;
            #pragma unroll
            for (int j = 0; j < N2d; ++j) {
                int hn = h * N2d + j;
                float er = __expf(dtv * -__expf(A_log[hn]));
                float s, cc;
                __sincosf(dtv * A_im[hn], &s, &cc);
                float ar = er * cc, ai = er * s;
                float gr = fmaf(ar, us, -us);
                float gi = ai * us;
                float nr = fmaf(ar, sr[j], fmaf(-ai, si[j], fmaf(gr, BAr[j], -gi * BAi[j])));
                float ni = fmaf(ar, si[j], fmaf( ai, sr[j], fmaf(gr, BAi[j],  gi * BAr[j])));
                sr[j] = nr; si[j] = ni;
            }
        }
        #pragma unroll
        for (int j = 0; j < N2d; ++j) {
            int hn = h * N2d + j;
            float er = __expf(sdt * -__expf(A_log[hn]));
            float s, cc;
            __sincosf(sdt * A_im[hn], &s, &cc);
            PS[c * NCH + j * Hd + h] = make_float4(er * cc, er * s, sr[j], si[j]);
        }
    }
}

// ---------------------------------------------------------------------------
// Kernel 3 (phase 2): serial combine over 256 chunks -> init state per chunk.
// ---------------------------------------------------------------------------
__global__ __launch_bounds__(256) void k_prefix(const float4* __restrict__ PS,
                                                float2* __restrict__ Ibuf) {
    int idx = blockIdx.x * 256 + threadIdx.x;  // 0..8191 = n*512+h
    float hr = 0.f, hi = 0.f;
    for (int b = 0; b < NCHUNK / 16; ++b) {
        float4 tp[16];
        #pragma unroll
        for (int i = 0; i < 16; ++i) tp[i] = PS[(b * 16 + i) * NCH + idx];
        #pragma unroll
        for (int i = 0; i < 16; ++i) {
            Ibuf[(b * 16 + i) * NCH + idx] = make_float2(hr, hi);
            float nr = fmaf(tp[i].x, hr, fmaf(-tp[i].y, hi, tp[i].z));
            float ni = fmaf(tp[i].x, hi, fmaf( tp[i].y, hr, tp[i].w));
            hr = nr; hi = ni;
        }
    }
}

// ---------------------------------------------------------------------------
// Kernel 4 (phase 3): re-scan with correct init; y fully in-register.
// ---------------------------------------------------------------------------
__global__ __launch_bounds__(256) void k_scan(const float* __restrict__ dtp,
        const float* __restrict__ usp,
        const float* __restrict__ A_log, const float* __restrict__ A_im,
        const float* __restrict__ B_param, const float* __restrict__ C_param,
        const float* __restrict__ Dp, const float2* __restrict__ Ibuf,
        float* __restrict__ out) {
    const int h = blockIdx.y * 256 + threadIdx.x;
    const int c = blockIdx.x;
    float Are0, Aim0, dA, BAr[N2d], BAi[N2d];
    const int mode = setup_h(A_log, A_im, B_param, h, Are0, Aim0, dA, BAr, BAi);
    float Cre[N2d], Cim[N2d];
    #pragma unroll
    for (int j = 0; j < N2d; ++j) {
        Cre[j] = C_param[2 * (h * N2d + j)];
        Cim[j] = C_param[2 * (h * N2d + j) + 1];
    }
    const float Dv = Dp[h];
    float sr[N2d], si[N2d];
    #pragma unroll
    for (int j = 0; j < N2d; ++j) {
        float2 h0 = Ibuf[c * NCH + j * Hd + h];
        sr[j] = h0.x; si[j] = h0.y;
    }
    const float* dp = dtp + (size_t)c * CLEN * Hd + h;
    const float* up = usp + (size_t)c * CLEN * Hd + h;
    float* op = out + (size_t)c * CLEN * Hd + h;
    if (mode == 2) {
        #pragma unroll 4
        for (int k = 0; k < CLEN; ++k) {
            float dtv = dp[k * Hd];
            float us  = up[k * Hd];
            float er = __expf(dtv * Are0);
            float sd, cd;
            __sincosf(dtv * dA, &sd, &cd);
            float yv;
            {
                float gr = fmaf(er, us, -us);
                float nr = fmaf(er, sr[0], gr * BAr[0]);
                float ni = fmaf(er, si[0], gr * BAi[0]);
                sr[0] = nr; si[0] = ni;
                yv = fmaf(nr, Cre[0], -ni * Cim[0]);
            }
            float ar = er * cd, ai = er * sd;
            #pragma unroll
            for (int j = 1; j < N2d; ++j) {
                float gr = fmaf(ar, us, -us);
                float gi = ai * us;
                float nr = fmaf(ar, sr[j], fmaf(-ai, si[j], fmaf(gr, BAr[j], -gi * BAi[j])));
                float ni = fmaf(ar, si[j], fmaf( ai, sr[j], fmaf(gr, BAi[j],  gi * BAr[j])));
                sr[j] = nr; si[j] = ni;
                yv = fmaf(nr, Cre[j], fmaf(-ni, Cim[j], yv));
                if (j < N2d - 1) {
                    float tr = fmaf(ar, cd, -ai * sd);
                    ai = fmaf(ai, cd, ar * sd);
                    ar = tr;
                }
            }
            op[k * Hd] = fmaf(dtv * us, Dv, yv);
        }
    } else if (mode == 1) {
        #pragma unroll 2
        for (int k = 0; k < CLEN; ++k) {
            float dtv = dp[k * Hd];
            float us  = up[k * Hd];
            float er = __expf(dtv * Are0);
            float s0, c0, sd, cd;
            __sincosf(dtv * Aim0, &s0, &c0);
            __sincosf(dtv * dA, &sd, &cd);
            float ar = er * c0, ai = er * s0;
            float yv = 0.f;
            #pragma unroll
            for (int j = 0; j < N2d; ++j) {
                float gr = fmaf(ar, us, -us);
                float gi = ai * us;
                float nr = fmaf(ar, sr[j], fmaf(-ai, si[j], fmaf(gr, BAr[j], -gi * BAi[j])));
                float ni = fmaf(ar, si[j], fmaf( ai, sr[j], fmaf(gr, BAi[j],  gi * BAr[j])));
                sr[j] = nr; si[j] = ni;
                yv = fmaf(nr, Cre[j], fmaf(-ni, Cim[j], yv));
                if (j < N2d - 1) {
                    float tr = fmaf(ar, cd, -ai * sd);
                    ai = fmaf(ai, cd, ar * sd);
                    ar = tr;
                }
            }
            op[k * Hd] = fmaf(dtv * us, Dv, yv);
        }
    } else {
        for (int k = 0; k < CLEN; ++k) {
            float dtv = dp[k * Hd];
            float us  = up[k * Hd];
            float yv = 0.f;
            #pragma unroll
            for (int j = 0; j < N2d; ++j) {
                int hn = h * N2d + j;
                float er = __expf(dtv * -__expf(A_log[hn]));
                float s, cc;
                __sincosf(dtv * A_im[hn], &s, &cc);
                float ar = er * cc, ai = er * s;
                float gr = fmaf(ar, us, -us);
                float gi = ai * us;
                float nr = fmaf(ar, sr[j], fmaf(-ai, si[j], fmaf(gr, BAr[j], -gi * BAi[j])));
                float ni = fmaf(ar, si[j], fmaf( ai, sr[j], fmaf(gr, BAi[j],  gi * BAr[j])));
                sr[j] = nr; si[j] = ni;
                yv = fmaf(nr, Cre[j], fmaf(-ni, Cim[j], yv));
            }
            op[k * Hd] = fmaf(dtv * us, Dv, yv);
        }
    }
}

extern "C" void kernel_launch(void* const* d_in, const int* in_sizes, int n_in,
                              void* d_out, int out_size, void* d_ws, size_t ws_size,
                              hipStream_t stream) {
    const float* u        = (const float*)d_in[0];
    const float* A_log    = (const float*)d_in[1];
    const float* A_im     = (const float*)d_in[2];
    const float* B_param  = (const float*)d_in[3];
    const float* C_param  = (const float*)d_in[4];
    const float* Dp       = (const float*)d_in[5];
    const float* dt_w     = (const float*)d_in[6];
    const float* dt_b     = (const float*)d_in[7];
    const float* xproj_w  = (const float*)d_in[8];

    // ws: dtp[L*H] | usp[L*H] | PS[NCHUNK*NCH f4] | I[NCHUNK*NCH f2] |
    //     dt_wT[R*H] | dt_u[L*R]
    float*  dtp  = (float*)d_ws;
    float*  usp  = dtp + (size_t)Ld * Hd;
    float4* PS   = (float4*)(usp + (size_t)Ld * Hd);
    float2* Ibuf = (float2*)(PS + (size_t)NCHUNK * NCH);
    float*  dt_wT = (float*)(Ibuf + (size_t)NCHUNK * NCH);
    float*  dt_u = dt_wT + (size_t)Rd * Hd;
    float*  out  = (float*)d_out;

    k_tw<<<(Rd * Hd) / 256, 256, 0, stream>>>(dt_w, dt_wT);
    k_dt1<<<Ld / 4, 256, 0, stream>>>(u, xproj_w, dt_u);
    dim3 gdt(Ld / 4, Hd / 256);
    k_dt2<<<gdt, 256, 0, stream>>>(u, dt_u, dt_wT, dt_b, dtp, usp);
    dim3 g2(NCHUNK, Hd / 256);
    k_chunk<<<g2, 256, 0, stream>>>(dtp, usp, A_log, A_im, B_param, PS);
    k_prefix<<<NCH / 256, 256, 0, stream>>>(PS, Ibuf);
    k_scan<<<g2, 256, 0, stream>>>(dtp, usp, A_log, A_im, B_param, C_param,
                                   Dp, Ibuf, out);
}